// Round 13
// baseline (5697.192 us; speedup 1.0000x reference)
//
#include <hip/hip_runtime.h>
#include <stdint.h>
#include <math.h>

// ---- problem constants ----
#define BATCH  128
#define NV     31999
#define NSTEP  50
#define NPB    1000          // vocab partial blocks (32 cols each)
#define TINYF  1.17549435e-38f

typedef __attribute__((ext_vector_type(8))) short bf16x8;
typedef __attribute__((ext_vector_type(4))) float f32x4;
typedef __attribute__((ext_vector_type(4))) unsigned int u32x4;

// ---------------- Threefry-2x32-20 (JAX exact) ----------------
__host__ __device__ __forceinline__ void tf2x32(uint32_t k0, uint32_t k1,
                                                uint32_t x0, uint32_t x1,
                                                uint32_t& o0, uint32_t& o1) {
  uint32_t k2 = k0 ^ k1 ^ 0x1BD11BDAu;
  x0 += k0; x1 += k1;
#define TF_R(r) { x0 += x1; x1 = (x1 << (r)) | (x1 >> (32 - (r))); x1 ^= x0; }
  TF_R(13) TF_R(15) TF_R(26) TF_R(6)
  x0 += k1; x1 += k2 + 1u;
  TF_R(17) TF_R(29) TF_R(16) TF_R(24)
  x0 += k2; x1 += k0 + 2u;
  TF_R(13) TF_R(15) TF_R(26) TF_R(6)
  x0 += k0; x1 += k1 + 3u;
  TF_R(17) TF_R(29) TF_R(16) TF_R(24)
  x0 += k1; x1 += k2 + 4u;
  TF_R(13) TF_R(15) TF_R(26) TF_R(6)
  x0 += k2; x1 += k0 + 5u;
#undef TF_R
  o0 = x0; o1 = x1;
}

__device__ __forceinline__ float sigm(float x) { return 1.0f / (1.0f + expf(-x)); }

__device__ __forceinline__ float gumbelv(uint32_t k0, uint32_t k1, uint32_t f) {
  uint32_t o0, o1; tf2x32(k0, k1, 0u, f, o0, o1);
  uint32_t bits = o0 ^ o1;
  float ff = __uint_as_float((bits >> 9) | 0x3f800000u) - 1.0f;
  float u = ff + TINYF;
  return -logf(-logf(u));
}

// bf16 split helpers (RNE)
__device__ __forceinline__ unsigned short bfhi(float x) {
  uint32_t u = __float_as_uint(x);
  u += 0x7fffu + ((u >> 16) & 1u);
  return (unsigned short)(u >> 16);
}
__device__ __forceinline__ void split2(float x, unsigned short& h, unsigned short& l) {
  unsigned short hh = bfhi(x);
  float hf = __uint_as_float(((uint32_t)hh) << 16);
  h = hh; l = bfhi(x - hf);
}

#define MFMA3(ah, al, bh, bl, c)                                            \
  c = __builtin_amdgcn_mfma_f32_16x16x32_bf16(ah, bh, c, 0, 0, 0);          \
  c = __builtin_amdgcn_mfma_f32_16x16x32_bf16(ah, bl, c, 0, 0, 0);          \
  c = __builtin_amdgcn_mfma_f32_16x16x32_bf16(al, bh, c, 0, 0, 0);

// ================= prologue fp32 GEMM (runs twice, small) =================
__global__ __launch_bounds__(256) void gemm_part(
    const float* __restrict__ A, int lda,
    const float* __restrict__ Wa, const float* __restrict__ Wb,
    int ks, int K, int N, int KC, float* __restrict__ part)
{
  __shared__ float As[32][132];
  __shared__ float Ws[32][68];
  const int tx = threadIdx.x;
  const int n0 = blockIdx.x * 64;
  const int kc = blockIdx.y;
  const int cg = tx & 15, rg = tx >> 4;
  float acc[8][4] = {};
  const int kend = (kc + 1) * KC;
  for (int kk = kc * KC; kk < kend; kk += 32) {
    __syncthreads();
#pragma unroll
    for (int i = 0; i < 16; ++i) {
      int e = tx + 256 * i; int b = e >> 5, k = e & 31;
      As[k][b] = A[b * lda + kk + k];
    }
#pragma unroll
    for (int i = 0; i < 8; ++i) {
      int e = tx + 256 * i; int n = e >> 5, k = e & 31;
      int nn = n0 + n, kg = kk + k;
      float w;
      if (kg < ks) w = Wa[(size_t)nn * ks + kg];
      else         w = Wb[(size_t)nn * (K - ks) + (kg - ks)];
      Ws[k][n] = w;
    }
    __syncthreads();
#pragma unroll
    for (int k = 0; k < 32; ++k) {
      float4 a0 = *(const float4*)&As[k][rg * 8];
      float4 a1 = *(const float4*)&As[k][rg * 8 + 4];
      float4 wv = *(const float4*)&Ws[k][cg * 4];
      float ar[8] = {a0.x, a0.y, a0.z, a0.w, a1.x, a1.y, a1.z, a1.w};
      float wr[4] = {wv.x, wv.y, wv.z, wv.w};
#pragma unroll
      for (int r = 0; r < 8; ++r)
#pragma unroll
        for (int c = 0; c < 4; ++c) acc[r][c] += ar[r] * wr[c];
    }
  }
  size_t base = (size_t)kc * BATCH * N;
#pragma unroll
  for (int r = 0; r < 8; ++r) {
    int row = rg * 8 + r;
    float4 v4 = make_float4(acc[r][0], acc[r][1], acc[r][2], acc[r][3]);
    *(float4*)&part[base + (size_t)row * N + n0 + cg * 4] = v4;
  }
}

__global__ void k_reduce_relu(const float* __restrict__ part, int nkc,
                              const float* __restrict__ bias,
                              float* __restrict__ out, int N) {
  int i = blockIdx.x * 256 + threadIdx.x;
  int n = i % N;
  float s = bias[n];
  for (int kc = 0; kc < nkc; ++kc) s += part[(size_t)kc * BATCH * N + i];
  out[i] = fmaxf(s, 0.0f);
}

__global__ void k_reduce_elu_split(const float* __restrict__ part, int nkc,
                                   const float* __restrict__ bias,
                                   unsigned short* __restrict__ xh,
                                   unsigned short* __restrict__ xl,
                                   float* __restrict__ cbuf) {
  int i = blockIdx.x * 256 + threadIdx.x;   // B*1024
  int b = i >> 10, n = i & 1023;
  float s = bias[n];
  for (int kc = 0; kc < nkc; ++kc) s += part[(size_t)kc * BATCH * 1024 + i];
  float e = (s > 0.0f) ? s : 0.1f * (expf(s) - 1.0f);
  if (n < 512) {
    unsigned short h_, l_; split2(e, h_, l_);
    xh[b * 1024 + 512 + n] = h_; xl[b * 1024 + 512 + n] = l_;
  } else cbuf[b * 512 + (n - 512)] = e;
}

__global__ void k_fill_e0(const float* __restrict__ emb,
                          unsigned short* __restrict__ xh,
                          unsigned short* __restrict__ xl) {
  int i = blockIdx.x * 256 + threadIdx.x;   // 128*512
  int b = i >> 9, k = i & 511;
  unsigned short h_, l_; split2(emb[k], h_, l_);
  xh[b * 1024 + k] = h_; xl[b * 1024 + k] = l_;
}

// ================= prep: split weights (vectorized x8) =================
__global__ void k_prep_gates(const float* __restrict__ Wih, const float* __restrict__ Whh,
                             const float* __restrict__ bih, const float* __restrict__ bhh,
                             unsigned short* __restrict__ Wh, unsigned short* __restrict__ Wl,
                             float* __restrict__ bg) {
  int i = blockIdx.x * 256 + threadIdx.x;
  int idx8 = i * 8;
  int n = idx8 >> 10, k0 = idx8 & 1023;
  const float* src = (k0 < 512) ? (Wih + (size_t)n * 512 + k0)
                                : (Whh + (size_t)n * 512 + (k0 - 512));
  float4 a = *(const float4*)src, b = *(const float4*)(src + 4);
  float wv[8] = {a.x, a.y, a.z, a.w, b.x, b.y, b.z, b.w};
  unsigned short hh[8], ll[8];
#pragma unroll
  for (int q = 0; q < 8; ++q) split2(wv[q], hh[q], ll[q]);
  u32x4 h4, l4;
#pragma unroll
  for (int q = 0; q < 4; ++q) {
    h4[q] = (uint32_t)hh[2 * q] | ((uint32_t)hh[2 * q + 1] << 16);
    l4[q] = (uint32_t)ll[2 * q] | ((uint32_t)ll[2 * q + 1] << 16);
  }
  *(u32x4*)(Wh + (size_t)idx8) = h4;
  *(u32x4*)(Wl + (size_t)idx8) = l4;
  if (i < 256) {
#pragma unroll
    for (int q = 0; q < 8; ++q) bg[i * 8 + q] = bih[i * 8 + q] + bhh[i * 8 + q];
  }
}

__global__ void k_prep_out1(const float* __restrict__ Wo1, const float* __restrict__ bo1,
                            const float* __restrict__ g, const float* __restrict__ bb,
                            const float* __restrict__ m, const float* __restrict__ v,
                            unsigned short* __restrict__ Wh, unsigned short* __restrict__ Wl,
                            float* __restrict__ S, float* __restrict__ T) {
  int i = blockIdx.x * 256 + threadIdx.x;
  int idx8 = i * 8;
  float4 a = *(const float4*)(Wo1 + idx8), b = *(const float4*)(Wo1 + idx8 + 4);
  float wv[8] = {a.x, a.y, a.z, a.w, b.x, b.y, b.z, b.w};
  unsigned short hh[8], ll[8];
#pragma unroll
  for (int q = 0; q < 8; ++q) split2(wv[q], hh[q], ll[q]);
  u32x4 h4, l4;
#pragma unroll
  for (int q = 0; q < 4; ++q) {
    h4[q] = (uint32_t)hh[2 * q] | ((uint32_t)hh[2 * q + 1] << 16);
    l4[q] = (uint32_t)ll[2 * q] | ((uint32_t)ll[2 * q + 1] << 16);
  }
  *(u32x4*)(Wh + (size_t)idx8) = h4;
  *(u32x4*)(Wl + (size_t)idx8) = l4;
  if (i < 128) {
#pragma unroll
    for (int q = 0; q < 8; ++q) {
      int n = i * 8 + q;
      float s = g[n] / sqrtf(v[n] + 1e-5f);
      S[n] = s;
      T[n] = (bo1[n] - m[n]) * s + bb[n];
    }
  }
}

__global__ void k_prep_wo2(const float* __restrict__ W,
                           unsigned short* __restrict__ Wh, unsigned short* __restrict__ Wl,
                           int total8) {
  int i = blockIdx.x * 256 + threadIdx.x;
  if (i >= total8) return;
  const float* wp = W + (size_t)i * 8;
  float4 a = *(const float4*)wp, b = *(const float4*)(wp + 4);
  float wv[8] = {a.x, a.y, a.z, a.w, b.x, b.y, b.z, b.w};
  unsigned short hh[8], ll[8];
#pragma unroll
  for (int q = 0; q < 8; ++q) split2(wv[q], hh[q], ll[q]);
  u32x4 h4, l4;
#pragma unroll
  for (int q = 0; q < 4; ++q) {
    h4[q] = (uint32_t)hh[2 * q] | ((uint32_t)hh[2 * q + 1] << 16);
    l4[q] = (uint32_t)ll[2 * q] | ((uint32_t)ll[2 * q + 1] << 16);
  }
  *(u32x4*)(Wh + (size_t)i * 8) = h4;
  *(u32x4*)(Wl + (size_t)i * 8) = l4;
}

// ================= fused gates MFMA + LSTM, depth-2 (unchanged) =================
// grid 32 blocks (16 j's each), block 256
__global__ __launch_bounds__(256) void k_gates(
    const unsigned short* __restrict__ Ah, const unsigned short* __restrict__ Al,
    const unsigned short* __restrict__ Wh, const unsigned short* __restrict__ Wl,
    const float* __restrict__ bg, float* __restrict__ cbuf,
    unsigned short* __restrict__ xh, unsigned short* __restrict__ xl,
    unsigned short* __restrict__ rhh, unsigned short* __restrict__ rhl)
{
  __shared__ __align__(16) unsigned char SM[40960];
  unsigned short (*WHb)[2][64][40] = (unsigned short(*)[2][64][40])SM;
  unsigned short (*WLb)[2][64][40] = (unsigned short(*)[2][64][40])(SM + 20480);
  const int tx = threadIdx.x;
  const int lane = tx & 63, w = tx >> 6;
  const int l15 = lane & 15, g4 = lane >> 4;
  const int gblk = blockIdx.x;
  const int arow0 = w * 32 + l15, ak = g4 * 8;
  const int sr = tx >> 2, sq = tx & 3;
  const int grow = (sr >> 4) * 512 + gblk * 16 + (sr & 15);
  const size_t wbase = (size_t)grow * 1024;

  f32x4 acc[2][4] = {};
  u32x4 RH[2][2], RL[2][2];
  bf16x8 QH[2][2][2], QL[2][2][2];

  auto ldW = [&](int set, int t) {
    const int kk = t * 64 + sq * 16;
    RH[set][0] = *(const u32x4*)(Wh + wbase + kk);
    RH[set][1] = *(const u32x4*)(Wh + wbase + kk + 8);
    RL[set][0] = *(const u32x4*)(Wl + wbase + kk);
    RL[set][1] = *(const u32x4*)(Wl + wbase + kk + 8);
  };
  auto stW = [&](int set, int buf) {
    const int kc = sq >> 1, ko = (sq & 1) * 16;
    *(u32x4*)&WHb[buf][kc][sr][ko]     = RH[set][0];
    *(u32x4*)&WHb[buf][kc][sr][ko + 8] = RH[set][1];
    *(u32x4*)&WLb[buf][kc][sr][ko]     = RL[set][0];
    *(u32x4*)&WLb[buf][kc][sr][ko + 8] = RL[set][1];
  };
  auto ldA = [&](int set, int t) {
#pragma unroll
    for (int rf = 0; rf < 2; ++rf)
#pragma unroll
      for (int kc = 0; kc < 2; ++kc) {
        size_t ao = (size_t)(arow0 + rf * 16) * 1024 + t * 64 + kc * 32 + ak;
        QH[set][rf][kc] = *(const bf16x8*)(Ah + ao);
        QL[set][rf][kc] = *(const bf16x8*)(Al + ao);
      }
  };
  auto comp = [&](int buf, int set) {
#pragma unroll
    for (int kc = 0; kc < 2; ++kc)
#pragma unroll
      for (int cf = 0; cf < 4; ++cf) {
        int col = cf * 16 + l15;
        bf16x8 bh = *(const bf16x8*)&WHb[buf][kc][col][ak];
        bf16x8 bl = *(const bf16x8*)&WLb[buf][kc][col][ak];
#pragma unroll
        for (int rf = 0; rf < 2; ++rf) { MFMA3(QH[set][rf][kc], QL[set][rf][kc], bh, bl, acc[rf][cf]); }
      }
  };

  ldW(0, 0); ldW(1, 1); ldA(0, 0);
  stW(0, 0); __syncthreads();
  for (int t = 0; t < 16; ++t) {
    const int pb = t & 1;
    if (t < 14) ldW(pb, t + 2);
    if (t < 15) ldA(pb ^ 1, t + 1);
    comp(pb, pb);
    if (t < 15) stW(pb ^ 1, pb ^ 1);
    __syncthreads();
  }
  // gate exchange via LDS (aliased over stage, safe after final barrier)
  float* gex = (float*)SM;   // [4][128][17]
#pragma unroll
  for (int rf = 0; rf < 2; ++rf)
#pragma unroll
    for (int cf = 0; cf < 4; ++cf)
#pragma unroll
      for (int r = 0; r < 4; ++r) {
        int brow = w * 32 + rf * 16 + g4 * 4 + r;
        gex[(cf * 128 + brow) * 17 + l15] = acc[rf][cf][r];
      }
  __syncthreads();
#pragma unroll
  for (int i = 0; i < 8; ++i) {
    int e = tx + 256 * i;                      // 0..2047
    int b = e >> 4, lj = e & 15;
    int jg = gblk * 16 + lj;
    float gi = gex[(0 * 128 + b) * 17 + lj] + bg[jg];
    float gf = gex[(1 * 128 + b) * 17 + lj] + bg[512 + jg];
    float gg = gex[(2 * 128 + b) * 17 + lj] + bg[1024 + jg];
    float go = gex[(3 * 128 + b) * 17 + lj] + bg[1536 + jg];
    float co = cbuf[b * 512 + jg];
    float cn = sigm(gf) * co + sigm(gi) * tanhf(gg);
    float hn = sigm(go) * tanhf(cn);
    cbuf[b * 512 + jg] = cn;
    unsigned short h_, l_;
    split2(hn, h_, l_);
    xh[b * 1024 + 512 + jg] = h_; xl[b * 1024 + 512 + jg] = l_;
    float r = fmaxf(hn, 0.0f);
    split2(r, h_, l_);
    rhh[b * 512 + jg] = h_; rhl[b * 512 + jg] = l_;
  }
}

// ================= fused Wo1 MFMA + BN + relu, depth-2 (unchanged) =================
// grid 16 blocks (64 cols each), block 256, K=512
__global__ __launch_bounds__(256) void k_out1(
    const unsigned short* __restrict__ Ah, const unsigned short* __restrict__ Al,
    const unsigned short* __restrict__ Wh, const unsigned short* __restrict__ Wl,
    const float* __restrict__ S, const float* __restrict__ T,
    unsigned short* __restrict__ r2h, unsigned short* __restrict__ r2l)
{
  __shared__ __align__(16) unsigned char SM[40960];
  unsigned short (*WHb)[2][64][40] = (unsigned short(*)[2][64][40])SM;
  unsigned short (*WLb)[2][64][40] = (unsigned short(*)[2][64][40])(SM + 20480);
  const int tx = threadIdx.x;
  const int lane = tx & 63, w = tx >> 6;
  const int l15 = lane & 15, g4 = lane >> 4;
  const int n0 = blockIdx.x * 64;
  const int arow0 = w * 32 + l15, ak = g4 * 8;
  const int sr = tx >> 2, sq = tx & 3;
  const size_t wbase = (size_t)(n0 + sr) * 512;

  f32x4 acc[2][4] = {};
  u32x4 RH[2][2], RL[2][2];
  bf16x8 QH[2][2][2], QL[2][2][2];

  auto ldW = [&](int set, int t) {
    const int kk = t * 64 + sq * 16;
    RH[set][0] = *(const u32x4*)(Wh + wbase + kk);
    RH[set][1] = *(const u32x4*)(Wh + wbase + kk + 8);
    RL[set][0] = *(const u32x4*)(Wl + wbase + kk);
    RL[set][1] = *(const u32x4*)(Wl + wbase + kk + 8);
  };
  auto stW = [&](int set, int buf) {
    const int kc = sq >> 1, ko = (sq & 1) * 16;
    *(u32x4*)&WHb[buf][kc][sr][ko]     = RH[set][0];
    *(u32x4*)&WHb[buf][kc][sr][ko + 8] = RH[set][1];
    *(u32x4*)&WLb[buf][kc][sr][ko]     = RL[set][0];
    *(u32x4*)&WLb[buf][kc][sr][ko + 8] = RL[set][1];
  };
  auto ldA = [&](int set, int t) {
#pragma unroll
    for (int rf = 0; rf < 2; ++rf)
#pragma unroll
      for (int kc = 0; kc < 2; ++kc) {
        size_t ao = (size_t)(arow0 + rf * 16) * 512 + t * 64 + kc * 32 + ak;
        QH[set][rf][kc] = *(const bf16x8*)(Ah + ao);
        QL[set][rf][kc] = *(const bf16x8*)(Al + ao);
      }
  };
  auto comp = [&](int buf, int set) {
#pragma unroll
    for (int kc = 0; kc < 2; ++kc)
#pragma unroll
      for (int cf = 0; cf < 4; ++cf) {
        int col = cf * 16 + l15;
        bf16x8 bh = *(const bf16x8*)&WHb[buf][kc][col][ak];
        bf16x8 bl = *(const bf16x8*)&WLb[buf][kc][col][ak];
#pragma unroll
        for (int rf = 0; rf < 2; ++rf) { MFMA3(QH[set][rf][kc], QL[set][rf][kc], bh, bl, acc[rf][cf]); }
      }
  };

  ldW(0, 0); ldW(1, 1); ldA(0, 0);
  stW(0, 0); __syncthreads();
  for (int t = 0; t < 8; ++t) {
    const int pb = t & 1;
    if (t < 6) ldW(pb, t + 2);
    if (t < 7) ldA(pb ^ 1, t + 1);
    comp(pb, pb);
    if (t < 7) stW(pb ^ 1, pb ^ 1);
    __syncthreads();
  }
#pragma unroll
  for (int cf = 0; cf < 4; ++cf) {
    int n = n0 + cf * 16 + l15;
    float s = S[n], t = T[n];
#pragma unroll
    for (int rf = 0; rf < 2; ++rf)
#pragma unroll
      for (int r = 0; r < 4; ++r) {
        int row = w * 32 + rf * 16 + g4 * 4 + r;
        float v = fmaxf(acc[rf][cf][r] * s + t, 0.0f);
        unsigned short h_, l_; split2(v, h_, l_);
        r2h[row * 1024 + n] = h_; r2l[row * 1024 + n] = l_;
      }
  }
}

// ====== fused vocab: 32 cols/block, 1000 blocks, 20KB LDS (4 blocks/CU) ======
// block 512 = 8 waves x 16 batch-rows; depth-3 W register prefetch; in-loop gumbel
template<int PRE>
__global__ __launch_bounds__(512, 4) void k_vocab(
    const unsigned short* __restrict__ Ah, const unsigned short* __restrict__ Al,
    const unsigned short* __restrict__ Wh, const unsigned short* __restrict__ Wl,
    const float* __restrict__ Wf, const float* __restrict__ bias,
    uint32_t key0, uint32_t key1,
    float* __restrict__ vpmax, float* __restrict__ vps1, float* __restrict__ vps2,
    float* __restrict__ vpbv, float* __restrict__ vpbl, int* __restrict__ vpbi)
{
  __shared__ __align__(16) unsigned char SM[20480];
  // WHb [2buf][2kc][32row][40] @0 (10240B), WLb same @10240
  unsigned short (*WHb)[2][32][40] = (unsigned short(*)[2][32][40])SM;
  unsigned short (*WLb)[2][32][40] = (unsigned short(*)[2][32][40])(SM + 10240);
  const int tx = threadIdx.x;
  const int lane = tx & 63, w = tx >> 6;          // 8 waves
  const int l15 = lane & 15, g4 = lane >> 4;
  const int n0 = blockIdx.x * 32;
  const int arow = w * 16 + l15, ak = g4 * 8;     // wave owns rows w*16..+15
  // staging: threads 0..255 stage Wh, 256..511 stage Wl; 32 rows x 8 thr/row x 16B
  const int sarr = tx >> 8;                        // 0 = Wh, 1 = Wl
  const int sr = (tx & 255) >> 3, sq = tx & 7;     // row 0..31, 16B chunk 0..7
  int grow = n0 + sr; if (grow >= NV) grow = NV - 1;
  const size_t wbase = (size_t)grow * 1024;
  const int skc = sq >> 2, sko = (sq & 3) * 8;
  const unsigned short* Wsrc = sarr ? Wl : Wh;

  f32x4 acc[2] = {};
  u32x4 R[3];
  float4 RF[3][2];
  bf16x8 QH[2][2], QL[2][2];
  float gvv[8];

  auto ldW = [&](int s, int t) {
    const int kk = t * 64 + sq * 8;
    if (PRE) {
      R[s] = *(const u32x4*)(Wsrc + wbase + kk);
    } else {
      RF[s][0] = *(const float4*)(Wf + wbase + kk);
      RF[s][1] = *(const float4*)(Wf + wbase + kk + 4);
    }
  };
  auto stW = [&](int s, int buf) {
    unsigned short* dst = sarr ? &WLb[buf][skc][sr][sko] : &WHb[buf][skc][sr][sko];
    if (PRE) {
      *(u32x4*)dst = R[s];
    } else {
      float fv[8] = {RF[s][0].x, RF[s][0].y, RF[s][0].z, RF[s][0].w,
                     RF[s][1].x, RF[s][1].y, RF[s][1].z, RF[s][1].w};
#pragma unroll
      for (int q = 0; q < 8; ++q) {
        unsigned short h_, l_; split2(fv[q], h_, l_);
        dst[q] = sarr ? l_ : h_;
      }
    }
  };
  auto ldA = [&](int s, int t) {
#pragma unroll
    for (int kc = 0; kc < 2; ++kc) {
      size_t ao = (size_t)arow * 1024 + t * 64 + kc * 32 + ak;
      QH[s][kc] = *(const bf16x8*)(Ah + ao);
      QL[s][kc] = *(const bf16x8*)(Al + ao);
    }
  };
  auto comp = [&](int buf, int s) {
#pragma unroll
    for (int kc = 0; kc < 2; ++kc)
#pragma unroll
      for (int cf = 0; cf < 2; ++cf) {
        int col = cf * 16 + l15;
        bf16x8 bh = *(const bf16x8*)&WHb[buf][kc][col][ak];
        bf16x8 bl = *(const bf16x8*)&WLb[buf][kc][col][ak];
        MFMA3(QH[s][kc], QL[s][kc], bh, bl, acc[cf]);
      }
  };

  ldW(0, 0); ldW(1, 1); ldW(2, 2); ldA(0, 0);
  stW(0, 0); __syncthreads();
#pragma unroll
  for (int t = 0; t < 16; ++t) {
    const int pb = t & 1;
    if (t < 13) ldW(t % 3, t + 3);
    if (t < 15) ldA((t + 1) & 1, t + 1);
    // in-loop gumbel (t compile-time): idx = reg*2+cf for t<8
    if (t < 8) {
      int row_t = w * 16 + g4 * 4 + (t >> 1);
      int v_t = n0 + (t & 1) * 16 + l15;
      if (v_t >= NV) v_t = 0;                    // unused for OOB cols
      gvv[t] = gumbelv(key0, key1, (uint32_t)row_t * 31999u + (uint32_t)v_t);
    }
    comp(pb, t & 1);
    if (t < 15) stW((t + 1) % 3, pb ^ 1);
    __syncthreads();
  }
  // ---- epilogue: bias + per-row partials (wave-local rows, 32 cols) ----
  float bias_c[2]; int vcol[2];
#pragma unroll
  for (int cf = 0; cf < 2; ++cf) {
    int v = n0 + cf * 16 + l15;
    vcol[cf] = v;
    bias_c[cf] = (v < NV) ? bias[v] : 0.0f;
  }
#pragma unroll
  for (int reg = 0; reg < 4; ++reg) {
    int row = w * 16 + g4 * 4 + reg;   // batch index
    float lv[2], pv[2];
    float mm = -INFINITY;
#pragma unroll
    for (int cf = 0; cf < 2; ++cf) {
      if (vcol[cf] < NV) {
        float l = acc[cf][reg] + bias_c[cf];
        lv[cf] = l; pv[cf] = l + gvv[reg * 2 + cf];
        mm = fmaxf(mm, l);
      } else { lv[cf] = -INFINITY; pv[cf] = -INFINITY; }
    }
    for (int d = 1; d <= 8; d <<= 1) mm = fmaxf(mm, __shfl_xor(mm, d));
    float s1 = 0.0f, s2 = 0.0f;
#pragma unroll
    for (int cf = 0; cf < 2; ++cf)
      if (vcol[cf] < NV) { float t = lv[cf] - mm; float e = expf(t); s1 += e; s2 += e * t; }
    for (int d = 1; d <= 8; d <<= 1) { s1 += __shfl_xor(s1, d); s2 += __shfl_xor(s2, d); }
    float bv = -INFINITY, bl_ = 0.0f; int bi = 0x7fffffff;
#pragma unroll
    for (int cf = 0; cf < 2; ++cf)
      if (pv[cf] > bv || (pv[cf] == bv && vcol[cf] < bi)) { bv = pv[cf]; bi = vcol[cf]; bl_ = lv[cf]; }
    for (int d = 1; d <= 8; d <<= 1) {
      float ov = __shfl_xor(bv, d); int oi = __shfl_xor(bi, d); float ol = __shfl_xor(bl_, d);
      if (ov > bv || (ov == bv && oi < bi)) { bv = ov; bi = oi; bl_ = ol; }
    }
    if (l15 == 0) {
      int o = row * NPB + blockIdx.x;
      vpmax[o] = mm; vps1[o] = s1; vps2[o] = s2;
      vpbv[o] = bv; vpbl[o] = bl_; vpbi[o] = bi;
    }
  }
}

// ================= per-row final reduce + sample + gather (256 thr) =================
__global__ __launch_bounds__(256) void k_final_sample(
    const float* __restrict__ vpmax, const float* __restrict__ vps1,
    const float* __restrict__ vps2, const float* __restrict__ vpbv,
    const float* __restrict__ vpbl, const int* __restrict__ vpbi,
    int t, int* __restrict__ xhist, float* __restrict__ lph,
    float* __restrict__ enth, const float* __restrict__ emb,
    unsigned short* __restrict__ xh, unsigned short* __restrict__ xl) {
  int b = blockIdx.x, tid = threadIdx.x;
  int lane = tid & 63, wv = tid >> 6;
  __shared__ float sM[4], sS1[4], sS2[4], sBV[4], sBL[4];
  __shared__ int sBI[4];
  float M = -INFINITY;
  for (int p = tid; p < NPB; p += 256) M = fmaxf(M, vpmax[b * NPB + p]);
  for (int d = 32; d; d >>= 1) M = fmaxf(M, __shfl_xor(M, d));
  if (lane == 0) sM[wv] = M;
  __syncthreads();
  M = fmaxf(fmaxf(sM[0], sM[1]), fmaxf(sM[2], sM[3]));
  float S1 = 0.0f, S2 = 0.0f, bv = -INFINITY, bl = 0.0f; int bi = 0x7fffffff;
  for (int p = tid; p < NPB; p += 256) {
    int o = b * NPB + p;
    float dm = vpmax[o] - M;
    float sc = expf(dm);
    S1 += vps1[o] * sc;
    S2 += (vps2[o] + dm * vps1[o]) * sc;
    float v = vpbv[o]; int ii = vpbi[o];
    if (v > bv || (v == bv && ii < bi)) { bv = v; bi = ii; bl = vpbl[o]; }
  }
  for (int d = 32; d; d >>= 1) {
    S1 += __shfl_xor(S1, d); S2 += __shfl_xor(S2, d);
    float ov = __shfl_xor(bv, d); int oi = __shfl_xor(bi, d); float ol = __shfl_xor(bl, d);
    if (ov > bv || (ov == bv && oi < bi)) { bv = ov; bi = oi; bl = ol; }
  }
  if (lane == 0) { sS1[wv] = S1; sS2[wv] = S2; sBV[wv] = bv; sBL[wv] = bl; sBI[wv] = bi; }
  __syncthreads();
  S1 = sS1[0] + sS1[1] + sS1[2] + sS1[3];
  S2 = sS2[0] + sS2[1] + sS2[2] + sS2[3];
  bv = -INFINITY; bi = 0x7fffffff; bl = 0.0f;
#pragma unroll
  for (int q = 0; q < 4; ++q) {
    if (sBV[q] > bv || (sBV[q] == bv && sBI[q] < bi)) { bv = sBV[q]; bi = sBI[q]; bl = sBL[q]; }
  }
  float logZ = logf(S1);
  if (tid == 0) {
    xhist[t * 128 + b] = bi;
    lph[t * 128 + b] = bl - M - logZ;
    enth[t * 128 + b] = logZ - S2 / S1;
  }
  const float* er = emb + (size_t)bi * 512;
  for (int k = tid; k < 512; k += 256) {
    unsigned short h_, l_; split2(er[k], h_, l_);
    xh[b * 1024 + k] = h_; xl[b * 1024 + k] = l_;
  }
}

// ================= output epilogue (fp32 out) =================
__global__ void k_finalize(const int* __restrict__ xhist, const float* __restrict__ lph,
                           const float* __restrict__ enth, float* __restrict__ out) {
  int b = blockIdx.x, lane = threadIdx.x;
  int tok = -1, cand = 1 << 20;
  if (lane < NSTEP) {
    tok = xhist[lane * 128 + b];
    if (tok == 1) cand = lane;
  }
  int e = cand;
  for (int d = 32; d; d >>= 1) e = min(e, __shfl_xor(e, d));
  int end_pos = (e >= (1 << 20)) ? 0 : e;
  int seq_len = end_pos + 1;
  if (seq_len == 1) seq_len = NSTEP;
  float ent = 0.0f;
  if (lane < NSTEP) {
    bool msk = lane < seq_len;
    out[b * NSTEP + lane]        = msk ? (float)(tok + 1) : 0.0f;
    out[6400 + b * NSTEP + lane] = msk ? lph[lane * 128 + b] : 0.0f;
    ent = msk ? enth[lane * 128 + b] : 0.0f;
  }
  for (int d = 32; d; d >>= 1) ent += __shfl_xor(ent, d);
  if (lane == 0) out[12800 + b] = ent / (float)seq_len;
}

// ================= host =================
extern "C" void kernel_launch(void* const* d_in, const int* in_sizes, int n_in,
                              void* d_out, int out_size, void* d_ws, size_t ws_size,
                              hipStream_t stream) {
  const float* z    = (const float*)d_in[0];
  const float* emb  = (const float*)d_in[1];
  const float* Wp1  = (const float*)d_in[2];
  const float* bp1  = (const float*)d_in[3];
  const float* Wp2  = (const float*)d_in[4];
  const float* bp2  = (const float*)d_in[5];
  const float* Wih  = (const float*)d_in[6];
  const float* Whh  = (const float*)d_in[7];
  const float* bih  = (const float*)d_in[8];
  const float* bhh  = (const float*)d_in[9];
  const float* Wo1  = (const float*)d_in[10];
  const float* bo1  = (const float*)d_in[11];
  const float* bng  = (const float*)d_in[12];
  const float* bnb  = (const float*)d_in[13];
  const float* bnm  = (const float*)d_in[14];
  const float* bnv  = (const float*)d_in[15];
  const float* Wo2  = (const float*)d_in[16];
  const float* bo2  = (const float*)d_in[17];
  float* out = (float*)d_out;
  (void)in_sizes; (void)n_in; (void)out_size;

  char* base = (char*)d_ws;
  size_t off = 0;
  auto alloc = [&](size_t bytes) -> void* {
    void* p = base + off;
    off = (off + bytes + 255) & ~(size_t)255;
    return p;
  };
  unsigned short* xh[2]; unsigned short* xl[2];
  xh[0] = (unsigned short*)alloc(128 * 1024 * 2);
  xl[0] = (unsigned short*)alloc(128 * 1024 * 2);
  xh[1] = (unsigned short*)alloc(128 * 1024 * 2);
  xl[1] = (unsigned short*)alloc(128 * 1024 * 2);
  float* cbuf = (float*)alloc(128 * 512 * 4);
  unsigned short* rhh = (unsigned short*)alloc(128 * 512 * 2);
  unsigned short* rhl = (unsigned short*)alloc(128 * 512 * 2);
  unsigned short* r2h = (unsigned short*)alloc(128 * 1024 * 2);
  unsigned short* r2l = (unsigned short*)alloc(128 * 1024 * 2);
  float* h1    = (float*)alloc(128 * 1024 * 4);
  float* apart = (float*)alloc((size_t)8 * 128 * 1024 * 4);
  unsigned short* Wgh = (unsigned short*)alloc((size_t)2048 * 1024 * 2);
  unsigned short* Wgl = (unsigned short*)alloc((size_t)2048 * 1024 * 2);
  float* bg = (float*)alloc(2048 * 4);
  unsigned short* Wo1h = (unsigned short*)alloc((size_t)1024 * 512 * 2);
  unsigned short* Wo1l = (unsigned short*)alloc((size_t)1024 * 512 * 2);
  float* Sbn = (float*)alloc(1024 * 4);
  float* Tbn = (float*)alloc(1024 * 4);
  float* vpmax = (float*)alloc((size_t)NPB * 128 * 4);
  float* vps1  = (float*)alloc((size_t)NPB * 128 * 4);
  float* vps2  = (float*)alloc((size_t)NPB * 128 * 4);
  float* vpbv  = (float*)alloc((size_t)NPB * 128 * 4);
  float* vpbl  = (float*)alloc((size_t)NPB * 128 * 4);
  int*   vpbi  = (int*)alloc((size_t)NPB * 128 * 4);
  int*   xhist = (int*)alloc(50 * 128 * 4);
  float* lph   = (float*)alloc(50 * 128 * 4);
  float* enth  = (float*)alloc(50 * 128 * 4);
  size_t wo2_elems = (size_t)NV * 1024;
  bool pre = ws_size >= off + 2 * wo2_elems * 2 + (1 << 20);
  unsigned short* Wo2h = nullptr; unsigned short* Wo2l = nullptr;
  if (pre) {
    Wo2h = (unsigned short*)alloc(wo2_elems * 2);
    Wo2l = (unsigned short*)alloc(wo2_elems * 2);
  }

  // step keys: partitionable split of key(42)
  uint32_t outk[100];
  for (int t = 0; t < 50; ++t) {
    uint32_t y0, y1;
    tf2x32(0u, 42u, 0u, (uint32_t)t, y0, y1);
    outk[2 * t] = y0; outk[2 * t + 1] = y1;
  }

  // prep (every launch; deterministic)
  k_prep_gates<<<1024, 256, 0, stream>>>(Wih, Whh, bih, bhh, Wgh, Wgl, bg);
  k_prep_out1<<<256, 256, 0, stream>>>(Wo1, bo1, bng, bnb, bnm, bnv, Wo1h, Wo1l, Sbn, Tbn);
  if (pre) {
    int total8 = (int)(wo2_elems / 8);
    k_prep_wo2<<<(total8 + 255) / 256, 256, 0, stream>>>(Wo2, Wo2h, Wo2l, total8);
  }

  // prologue: e0 + (h,c) projection
  k_fill_e0<<<256, 256, 0, stream>>>(emb, xh[0], xl[0]);
  gemm_part<<<dim3(16, 4), 256, 0, stream>>>(z, 512, Wp1, Wp1, 512, 512, 1024, 128, apart);
  k_reduce_relu<<<512, 256, 0, stream>>>(apart, 4, bp1, h1, 1024);
  gemm_part<<<dim3(16, 8), 256, 0, stream>>>(h1, 1024, Wp2, Wp2, 1024, 1024, 1024, 128, apart);
  k_reduce_elu_split<<<512, 256, 0, stream>>>(apart, 8, bp2, xh[0], xl[0], cbuf);

  for (int t = 0; t < NSTEP; ++t) {
    int ri = t & 1, wi = ri ^ 1;
    k_gates<<<32, 256, 0, stream>>>(xh[ri], xl[ri], Wgh, Wgl, bg, cbuf,
                                    xh[wi], xl[wi], rhh, rhl);
    k_out1<<<16, 256, 0, stream>>>(rhh, rhl, Wo1h, Wo1l, Sbn, Tbn, r2h, r2l);
    if (pre)
      k_vocab<1><<<NPB, 512, 0, stream>>>(r2h, r2l, Wo2h, Wo2l, Wo2, bo2,
                                          outk[2 * t], outk[2 * t + 1],
                                          vpmax, vps1, vps2, vpbv, vpbl, vpbi);
    else
      k_vocab<0><<<NPB, 512, 0, stream>>>(r2h, r2l, nullptr, nullptr, Wo2, bo2,
                                          outk[2 * t], outk[2 * t + 1],
                                          vpmax, vps1, vps2, vpbv, vpbl, vpbi);
    k_final_sample<<<128, 256, 0, stream>>>(vpmax, vps1, vps2, vpbv, vpbl, vpbi,
                                            t, xhist, lph, enth, emb, xh[wi], xl[wi]);
  }
  k_finalize<<<128, 64, 0, stream>>>(xhist, lph, enth, out);
}

// Round 14
// 4265.406 us; speedup vs baseline: 1.3357x; 1.3357x over previous
//
#include <hip/hip_runtime.h>
#include <stdint.h>
#include <math.h>

// ---- problem constants ----
#define BATCH  128
#define NV     31999
#define NSTEP  50
#define NPB    500           // vocab partial blocks (64 cols each)
#define TINYF  1.17549435e-38f

typedef __attribute__((ext_vector_type(8))) short bf16x8;
typedef __attribute__((ext_vector_type(4))) float f32x4;
typedef __attribute__((ext_vector_type(4))) unsigned int u32x4;

// ---------------- Threefry-2x32-20 (JAX exact) ----------------
__host__ __device__ __forceinline__ void tf2x32(uint32_t k0, uint32_t k1,
                                                uint32_t x0, uint32_t x1,
                                                uint32_t& o0, uint32_t& o1) {
  uint32_t k2 = k0 ^ k1 ^ 0x1BD11BDAu;
  x0 += k0; x1 += k1;
#define TF_R(r) { x0 += x1; x1 = (x1 << (r)) | (x1 >> (32 - (r))); x1 ^= x0; }
  TF_R(13) TF_R(15) TF_R(26) TF_R(6)
  x0 += k1; x1 += k2 + 1u;
  TF_R(17) TF_R(29) TF_R(16) TF_R(24)
  x0 += k2; x1 += k0 + 2u;
  TF_R(13) TF_R(15) TF_R(26) TF_R(6)
  x0 += k0; x1 += k1 + 3u;
  TF_R(17) TF_R(29) TF_R(16) TF_R(24)
  x0 += k1; x1 += k2 + 4u;
  TF_R(13) TF_R(15) TF_R(26) TF_R(6)
  x0 += k2; x1 += k0 + 5u;
#undef TF_R
  o0 = x0; o1 = x1;
}

__device__ __forceinline__ float sigm(float x) { return 1.0f / (1.0f + expf(-x)); }

__device__ __forceinline__ float gumbelv(uint32_t k0, uint32_t k1, uint32_t f) {
  uint32_t o0, o1; tf2x32(k0, k1, 0u, f, o0, o1);
  uint32_t bits = o0 ^ o1;
  float ff = __uint_as_float((bits >> 9) | 0x3f800000u) - 1.0f;
  float u = ff + TINYF;
  return -logf(-logf(u));
}

// bf16 split helpers (RNE)
__device__ __forceinline__ unsigned short bfhi(float x) {
  uint32_t u = __float_as_uint(x);
  u += 0x7fffu + ((u >> 16) & 1u);
  return (unsigned short)(u >> 16);
}
__device__ __forceinline__ void split2(float x, unsigned short& h, unsigned short& l) {
  unsigned short hh = bfhi(x);
  float hf = __uint_as_float(((uint32_t)hh) << 16);
  h = hh; l = bfhi(x - hf);
}

#define MFMA3(ah, al, bh, bl, c)                                            \
  c = __builtin_amdgcn_mfma_f32_16x16x32_bf16(ah, bh, c, 0, 0, 0);          \
  c = __builtin_amdgcn_mfma_f32_16x16x32_bf16(ah, bl, c, 0, 0, 0);          \
  c = __builtin_amdgcn_mfma_f32_16x16x32_bf16(al, bh, c, 0, 0, 0);

// ================= prologue fp32 GEMM (runs twice, small) =================
__global__ __launch_bounds__(256) void gemm_part(
    const float* __restrict__ A, int lda,
    const float* __restrict__ Wa, const float* __restrict__ Wb,
    int ks, int K, int N, int KC, float* __restrict__ part)
{
  __shared__ float As[32][132];
  __shared__ float Ws[32][68];
  const int tx = threadIdx.x;
  const int n0 = blockIdx.x * 64;
  const int kc = blockIdx.y;
  const int cg = tx & 15, rg = tx >> 4;
  float acc[8][4] = {};
  const int kend = (kc + 1) * KC;
  for (int kk = kc * KC; kk < kend; kk += 32) {
    __syncthreads();
#pragma unroll
    for (int i = 0; i < 16; ++i) {
      int e = tx + 256 * i; int b = e >> 5, k = e & 31;
      As[k][b] = A[b * lda + kk + k];
    }
#pragma unroll
    for (int i = 0; i < 8; ++i) {
      int e = tx + 256 * i; int n = e >> 5, k = e & 31;
      int nn = n0 + n, kg = kk + k;
      float w;
      if (kg < ks) w = Wa[(size_t)nn * ks + kg];
      else         w = Wb[(size_t)nn * (K - ks) + (kg - ks)];
      Ws[k][n] = w;
    }
    __syncthreads();
#pragma unroll
    for (int k = 0; k < 32; ++k) {
      float4 a0 = *(const float4*)&As[k][rg * 8];
      float4 a1 = *(const float4*)&As[k][rg * 8 + 4];
      float4 wv = *(const float4*)&Ws[k][cg * 4];
      float ar[8] = {a0.x, a0.y, a0.z, a0.w, a1.x, a1.y, a1.z, a1.w};
      float wr[4] = {wv.x, wv.y, wv.z, wv.w};
#pragma unroll
      for (int r = 0; r < 8; ++r)
#pragma unroll
        for (int c = 0; c < 4; ++c) acc[r][c] += ar[r] * wr[c];
    }
  }
  size_t base = (size_t)kc * BATCH * N;
#pragma unroll
  for (int r = 0; r < 8; ++r) {
    int row = rg * 8 + r;
    float4 v4 = make_float4(acc[r][0], acc[r][1], acc[r][2], acc[r][3]);
    *(float4*)&part[base + (size_t)row * N + n0 + cg * 4] = v4;
  }
}

__global__ void k_reduce_relu(const float* __restrict__ part, int nkc,
                              const float* __restrict__ bias,
                              float* __restrict__ out, int N) {
  int i = blockIdx.x * 256 + threadIdx.x;
  int n = i % N;
  float s = bias[n];
  for (int kc = 0; kc < nkc; ++kc) s += part[(size_t)kc * BATCH * N + i];
  out[i] = fmaxf(s, 0.0f);
}

__global__ void k_reduce_elu_split(const float* __restrict__ part, int nkc,
                                   const float* __restrict__ bias,
                                   unsigned short* __restrict__ xh,
                                   unsigned short* __restrict__ xl,
                                   float* __restrict__ cbuf) {
  int i = blockIdx.x * 256 + threadIdx.x;   // B*1024
  int b = i >> 10, n = i & 1023;
  float s = bias[n];
  for (int kc = 0; kc < nkc; ++kc) s += part[(size_t)kc * BATCH * 1024 + i];
  float e = (s > 0.0f) ? s : 0.1f * (expf(s) - 1.0f);
  if (n < 512) {
    unsigned short h_, l_; split2(e, h_, l_);
    xh[b * 1024 + 512 + n] = h_; xl[b * 1024 + 512 + n] = l_;
  } else cbuf[b * 512 + (n - 512)] = e;
}

__global__ void k_fill_e0(const float* __restrict__ emb,
                          unsigned short* __restrict__ xh,
                          unsigned short* __restrict__ xl) {
  int i = blockIdx.x * 256 + threadIdx.x;   // 128*512
  int b = i >> 9, k = i & 511;
  unsigned short h_, l_; split2(emb[k], h_, l_);
  xh[b * 1024 + k] = h_; xl[b * 1024 + k] = l_;
}

// ================= prep: split weights (vectorized x8) =================
__global__ void k_prep_gates(const float* __restrict__ Wih, const float* __restrict__ Whh,
                             const float* __restrict__ bih, const float* __restrict__ bhh,
                             unsigned short* __restrict__ Wh, unsigned short* __restrict__ Wl,
                             float* __restrict__ bg) {
  int i = blockIdx.x * 256 + threadIdx.x;
  int idx8 = i * 8;
  int n = idx8 >> 10, k0 = idx8 & 1023;
  const float* src = (k0 < 512) ? (Wih + (size_t)n * 512 + k0)
                                : (Whh + (size_t)n * 512 + (k0 - 512));
  float4 a = *(const float4*)src, b = *(const float4*)(src + 4);
  float wv[8] = {a.x, a.y, a.z, a.w, b.x, b.y, b.z, b.w};
  unsigned short hh[8], ll[8];
#pragma unroll
  for (int q = 0; q < 8; ++q) split2(wv[q], hh[q], ll[q]);
  u32x4 h4, l4;
#pragma unroll
  for (int q = 0; q < 4; ++q) {
    h4[q] = (uint32_t)hh[2 * q] | ((uint32_t)hh[2 * q + 1] << 16);
    l4[q] = (uint32_t)ll[2 * q] | ((uint32_t)ll[2 * q + 1] << 16);
  }
  *(u32x4*)(Wh + (size_t)idx8) = h4;
  *(u32x4*)(Wl + (size_t)idx8) = l4;
  if (i < 256) {
#pragma unroll
    for (int q = 0; q < 8; ++q) bg[i * 8 + q] = bih[i * 8 + q] + bhh[i * 8 + q];
  }
}

__global__ void k_prep_out1(const float* __restrict__ Wo1, const float* __restrict__ bo1,
                            const float* __restrict__ g, const float* __restrict__ bb,
                            const float* __restrict__ m, const float* __restrict__ v,
                            unsigned short* __restrict__ Wh, unsigned short* __restrict__ Wl,
                            float* __restrict__ S, float* __restrict__ T) {
  int i = blockIdx.x * 256 + threadIdx.x;
  int idx8 = i * 8;
  float4 a = *(const float4*)(Wo1 + idx8), b = *(const float4*)(Wo1 + idx8 + 4);
  float wv[8] = {a.x, a.y, a.z, a.w, b.x, b.y, b.z, b.w};
  unsigned short hh[8], ll[8];
#pragma unroll
  for (int q = 0; q < 8; ++q) split2(wv[q], hh[q], ll[q]);
  u32x4 h4, l4;
#pragma unroll
  for (int q = 0; q < 4; ++q) {
    h4[q] = (uint32_t)hh[2 * q] | ((uint32_t)hh[2 * q + 1] << 16);
    l4[q] = (uint32_t)ll[2 * q] | ((uint32_t)ll[2 * q + 1] << 16);
  }
  *(u32x4*)(Wh + (size_t)idx8) = h4;
  *(u32x4*)(Wl + (size_t)idx8) = l4;
  if (i < 128) {
#pragma unroll
    for (int q = 0; q < 8; ++q) {
      int n = i * 8 + q;
      float s = g[n] / sqrtf(v[n] + 1e-5f);
      S[n] = s;
      T[n] = (bo1[n] - m[n]) * s + bb[n];
    }
  }
}

__global__ void k_prep_wo2(const float* __restrict__ W,
                           unsigned short* __restrict__ Wh, unsigned short* __restrict__ Wl,
                           int total8) {
  int i = blockIdx.x * 256 + threadIdx.x;
  if (i >= total8) return;
  const float* wp = W + (size_t)i * 8;
  float4 a = *(const float4*)wp, b = *(const float4*)(wp + 4);
  float wv[8] = {a.x, a.y, a.z, a.w, b.x, b.y, b.z, b.w};
  unsigned short hh[8], ll[8];
#pragma unroll
  for (int q = 0; q < 8; ++q) split2(wv[q], hh[q], ll[q]);
  u32x4 h4, l4;
#pragma unroll
  for (int q = 0; q < 4; ++q) {
    h4[q] = (uint32_t)hh[2 * q] | ((uint32_t)hh[2 * q + 1] << 16);
    l4[q] = (uint32_t)ll[2 * q] | ((uint32_t)ll[2 * q + 1] << 16);
  }
  *(u32x4*)(Wh + (size_t)i * 8) = h4;
  *(u32x4*)(Wl + (size_t)i * 8) = l4;
}

// ================= fused gates MFMA + LSTM, depth-2 (unchanged) =================
// grid 32 blocks (16 j's each), block 256
__global__ __launch_bounds__(256) void k_gates(
    const unsigned short* __restrict__ Ah, const unsigned short* __restrict__ Al,
    const unsigned short* __restrict__ Wh, const unsigned short* __restrict__ Wl,
    const float* __restrict__ bg, float* __restrict__ cbuf,
    unsigned short* __restrict__ xh, unsigned short* __restrict__ xl,
    unsigned short* __restrict__ rhh, unsigned short* __restrict__ rhl)
{
  __shared__ __align__(16) unsigned char SM[40960];
  unsigned short (*WHb)[2][64][40] = (unsigned short(*)[2][64][40])SM;
  unsigned short (*WLb)[2][64][40] = (unsigned short(*)[2][64][40])(SM + 20480);
  const int tx = threadIdx.x;
  const int lane = tx & 63, w = tx >> 6;
  const int l15 = lane & 15, g4 = lane >> 4;
  const int gblk = blockIdx.x;
  const int arow0 = w * 32 + l15, ak = g4 * 8;
  const int sr = tx >> 2, sq = tx & 3;
  const int grow = (sr >> 4) * 512 + gblk * 16 + (sr & 15);
  const size_t wbase = (size_t)grow * 1024;

  f32x4 acc[2][4] = {};
  u32x4 RH[2][2], RL[2][2];
  bf16x8 QH[2][2][2], QL[2][2][2];

  auto ldW = [&](int set, int t) {
    const int kk = t * 64 + sq * 16;
    RH[set][0] = *(const u32x4*)(Wh + wbase + kk);
    RH[set][1] = *(const u32x4*)(Wh + wbase + kk + 8);
    RL[set][0] = *(const u32x4*)(Wl + wbase + kk);
    RL[set][1] = *(const u32x4*)(Wl + wbase + kk + 8);
  };
  auto stW = [&](int set, int buf) {
    const int kc = sq >> 1, ko = (sq & 1) * 16;
    *(u32x4*)&WHb[buf][kc][sr][ko]     = RH[set][0];
    *(u32x4*)&WHb[buf][kc][sr][ko + 8] = RH[set][1];
    *(u32x4*)&WLb[buf][kc][sr][ko]     = RL[set][0];
    *(u32x4*)&WLb[buf][kc][sr][ko + 8] = RL[set][1];
  };
  auto ldA = [&](int set, int t) {
#pragma unroll
    for (int rf = 0; rf < 2; ++rf)
#pragma unroll
      for (int kc = 0; kc < 2; ++kc) {
        size_t ao = (size_t)(arow0 + rf * 16) * 1024 + t * 64 + kc * 32 + ak;
        QH[set][rf][kc] = *(const bf16x8*)(Ah + ao);
        QL[set][rf][kc] = *(const bf16x8*)(Al + ao);
      }
  };
  auto comp = [&](int buf, int set) {
#pragma unroll
    for (int kc = 0; kc < 2; ++kc)
#pragma unroll
      for (int cf = 0; cf < 4; ++cf) {
        int col = cf * 16 + l15;
        bf16x8 bh = *(const bf16x8*)&WHb[buf][kc][col][ak];
        bf16x8 bl = *(const bf16x8*)&WLb[buf][kc][col][ak];
#pragma unroll
        for (int rf = 0; rf < 2; ++rf) { MFMA3(QH[set][rf][kc], QL[set][rf][kc], bh, bl, acc[rf][cf]); }
      }
  };

  ldW(0, 0); ldW(1, 1); ldA(0, 0);
  stW(0, 0); __syncthreads();
  for (int t = 0; t < 16; ++t) {
    const int pb = t & 1;
    if (t < 14) ldW(pb, t + 2);
    if (t < 15) ldA(pb ^ 1, t + 1);
    comp(pb, pb);
    if (t < 15) stW(pb ^ 1, pb ^ 1);
    __syncthreads();
  }
  // gate exchange via LDS (aliased over stage, safe after final barrier)
  float* gex = (float*)SM;   // [4][128][17]
#pragma unroll
  for (int rf = 0; rf < 2; ++rf)
#pragma unroll
    for (int cf = 0; cf < 4; ++cf)
#pragma unroll
      for (int r = 0; r < 4; ++r) {
        int brow = w * 32 + rf * 16 + g4 * 4 + r;
        gex[(cf * 128 + brow) * 17 + l15] = acc[rf][cf][r];
      }
  __syncthreads();
#pragma unroll
  for (int i = 0; i < 8; ++i) {
    int e = tx + 256 * i;                      // 0..2047
    int b = e >> 4, lj = e & 15;
    int jg = gblk * 16 + lj;
    float gi = gex[(0 * 128 + b) * 17 + lj] + bg[jg];
    float gf = gex[(1 * 128 + b) * 17 + lj] + bg[512 + jg];
    float gg = gex[(2 * 128 + b) * 17 + lj] + bg[1024 + jg];
    float go = gex[(3 * 128 + b) * 17 + lj] + bg[1536 + jg];
    float co = cbuf[b * 512 + jg];
    float cn = sigm(gf) * co + sigm(gi) * tanhf(gg);
    float hn = sigm(go) * tanhf(cn);
    cbuf[b * 512 + jg] = cn;
    unsigned short h_, l_;
    split2(hn, h_, l_);
    xh[b * 1024 + 512 + jg] = h_; xl[b * 1024 + 512 + jg] = l_;
    float r = fmaxf(hn, 0.0f);
    split2(r, h_, l_);
    rhh[b * 512 + jg] = h_; rhl[b * 512 + jg] = l_;
  }
}

// ================= fused Wo1 MFMA + BN + relu, depth-2 (unchanged) =================
// grid 16 blocks (64 cols each), block 256, K=512
__global__ __launch_bounds__(256) void k_out1(
    const unsigned short* __restrict__ Ah, const unsigned short* __restrict__ Al,
    const unsigned short* __restrict__ Wh, const unsigned short* __restrict__ Wl,
    const float* __restrict__ S, const float* __restrict__ T,
    unsigned short* __restrict__ r2h, unsigned short* __restrict__ r2l)
{
  __shared__ __align__(16) unsigned char SM[40960];
  unsigned short (*WHb)[2][64][40] = (unsigned short(*)[2][64][40])SM;
  unsigned short (*WLb)[2][64][40] = (unsigned short(*)[2][64][40])(SM + 20480);
  const int tx = threadIdx.x;
  const int lane = tx & 63, w = tx >> 6;
  const int l15 = lane & 15, g4 = lane >> 4;
  const int n0 = blockIdx.x * 64;
  const int arow0 = w * 32 + l15, ak = g4 * 8;
  const int sr = tx >> 2, sq = tx & 3;
  const size_t wbase = (size_t)(n0 + sr) * 512;

  f32x4 acc[2][4] = {};
  u32x4 RH[2][2], RL[2][2];
  bf16x8 QH[2][2][2], QL[2][2][2];

  auto ldW = [&](int set, int t) {
    const int kk = t * 64 + sq * 16;
    RH[set][0] = *(const u32x4*)(Wh + wbase + kk);
    RH[set][1] = *(const u32x4*)(Wh + wbase + kk + 8);
    RL[set][0] = *(const u32x4*)(Wl + wbase + kk);
    RL[set][1] = *(const u32x4*)(Wl + wbase + kk + 8);
  };
  auto stW = [&](int set, int buf) {
    const int kc = sq >> 1, ko = (sq & 1) * 16;
    *(u32x4*)&WHb[buf][kc][sr][ko]     = RH[set][0];
    *(u32x4*)&WHb[buf][kc][sr][ko + 8] = RH[set][1];
    *(u32x4*)&WLb[buf][kc][sr][ko]     = RL[set][0];
    *(u32x4*)&WLb[buf][kc][sr][ko + 8] = RL[set][1];
  };
  auto ldA = [&](int set, int t) {
#pragma unroll
    for (int rf = 0; rf < 2; ++rf)
#pragma unroll
      for (int kc = 0; kc < 2; ++kc) {
        size_t ao = (size_t)(arow0 + rf * 16) * 512 + t * 64 + kc * 32 + ak;
        QH[set][rf][kc] = *(const bf16x8*)(Ah + ao);
        QL[set][rf][kc] = *(const bf16x8*)(Al + ao);
      }
  };
  auto comp = [&](int buf, int set) {
#pragma unroll
    for (int kc = 0; kc < 2; ++kc)
#pragma unroll
      for (int cf = 0; cf < 4; ++cf) {
        int col = cf * 16 + l15;
        bf16x8 bh = *(const bf16x8*)&WHb[buf][kc][col][ak];
        bf16x8 bl = *(const bf16x8*)&WLb[buf][kc][col][ak];
#pragma unroll
        for (int rf = 0; rf < 2; ++rf) { MFMA3(QH[set][rf][kc], QL[set][rf][kc], bh, bl, acc[rf][cf]); }
      }
  };

  ldW(0, 0); ldW(1, 1); ldA(0, 0);
  stW(0, 0); __syncthreads();
  for (int t = 0; t < 8; ++t) {
    const int pb = t & 1;
    if (t < 6) ldW(pb, t + 2);
    if (t < 7) ldA(pb ^ 1, t + 1);
    comp(pb, pb);
    if (t < 7) stW(pb ^ 1, pb ^ 1);
    __syncthreads();
  }
#pragma unroll
  for (int cf = 0; cf < 4; ++cf) {
    int n = n0 + cf * 16 + l15;
    float s = S[n], t = T[n];
#pragma unroll
    for (int rf = 0; rf < 2; ++rf)
#pragma unroll
      for (int r = 0; r < 4; ++r) {
        int row = w * 32 + rf * 16 + g4 * 4 + r;
        float v = fmaxf(acc[rf][cf][r] * s + t, 0.0f);
        unsigned short h_, l_; split2(v, h_, l_);
        r2h[row * 1024 + n] = h_; r2l[row * 1024 + n] = l_;
      }
  }
}

// === fused vocab: R12 structure + 4-buffer LDS, barrier every 2 sub-iters ===
// grid 500 blocks (64 cols), block 512 (8 waves x 16 batch-rows), K=1024
// W prefetch: 4 register sets (mod-4), chunk c in set c&3; buf c&3 holds chunk c.
template<int PRE>
__global__ __launch_bounds__(512, 4) void k_vocab(
    const unsigned short* __restrict__ Ah, const unsigned short* __restrict__ Al,
    const unsigned short* __restrict__ Wh, const unsigned short* __restrict__ Wl,
    const float* __restrict__ Wf, const float* __restrict__ bias,
    uint32_t key0, uint32_t key1,
    float* __restrict__ vpmax, float* __restrict__ vps1, float* __restrict__ vps2,
    float* __restrict__ vpbv, float* __restrict__ vpbl, int* __restrict__ vpbi)
{
  __shared__ __align__(16) unsigned char SM[81920];
  unsigned short (*WHb)[2][64][40] = (unsigned short(*)[2][64][40])SM;             // [4][2][64][40]
  unsigned short (*WLb)[2][64][40] = (unsigned short(*)[2][64][40])(SM + 40960);
  const int tx = threadIdx.x;
  const int lane = tx & 63, w = tx >> 6;          // 8 waves
  const int l15 = lane & 15, g4 = lane >> 4;
  const int n0 = blockIdx.x * 64;
  const int arow = w * 16 + l15, ak = g4 * 8;     // wave owns rows w*16..+15
  const int sr = tx >> 3, sq = tx & 7;            // 64 W-rows, 8 thr/row (16B each)
  int grow = n0 + sr; if (grow >= NV) grow = NV - 1;
  const size_t wbase = (size_t)grow * 1024;
  const int skc = sq >> 2, sko = (sq & 3) * 8;

  f32x4 acc[4] = {};
  u32x4 RH[4], RL[4];
  float4 RF[4][2];
  bf16x8 QH[2][2], QL[2][2];
  float gvv[16];

  auto ldW = [&](int s, int t) {
    const int kk = t * 64 + sq * 8;
    if (PRE) {
      RH[s] = *(const u32x4*)(Wh + wbase + kk);
      RL[s] = *(const u32x4*)(Wl + wbase + kk);
    } else {
      RF[s][0] = *(const float4*)(Wf + wbase + kk);
      RF[s][1] = *(const float4*)(Wf + wbase + kk + 4);
    }
  };
  auto stW = [&](int s, int buf) {
    if (PRE) {
      *(u32x4*)&WHb[buf][skc][sr][sko] = RH[s];
      *(u32x4*)&WLb[buf][skc][sr][sko] = RL[s];
    } else {
      float fv[8] = {RF[s][0].x, RF[s][0].y, RF[s][0].z, RF[s][0].w,
                     RF[s][1].x, RF[s][1].y, RF[s][1].z, RF[s][1].w};
      unsigned short hh[8], ll[8];
#pragma unroll
      for (int q = 0; q < 8; ++q) split2(fv[q], hh[q], ll[q]);
#pragma unroll
      for (int q = 0; q < 8; ++q) { WHb[buf][skc][sr][sko + q] = hh[q]; WLb[buf][skc][sr][sko + q] = ll[q]; }
    }
  };
  auto ldA = [&](int s, int t) {
#pragma unroll
    for (int kc = 0; kc < 2; ++kc) {
      size_t ao = (size_t)arow * 1024 + t * 64 + kc * 32 + ak;
      QH[s][kc] = *(const bf16x8*)(Ah + ao);
      QL[s][kc] = *(const bf16x8*)(Al + ao);
    }
  };
  auto comp = [&](int buf, int s) {
#pragma unroll
    for (int kc = 0; kc < 2; ++kc)
#pragma unroll
      for (int cf = 0; cf < 4; ++cf) {
        int col = cf * 16 + l15;
        bf16x8 bh = *(const bf16x8*)&WHb[buf][kc][col][ak];
        bf16x8 bl = *(const bf16x8*)&WLb[buf][kc][col][ak];
        MFMA3(QH[s][kc], QL[s][kc], bh, bl, acc[cf]);
      }
  };
  auto gum = [&](int t) {                        // t compile-time
    int row_t = w * 16 + g4 * 4 + (t >> 2);
    int v_t = n0 + (t & 3) * 16 + l15;
    if (v_t >= NV) v_t = 0;                      // unused for OOB cols
    gvv[t] = gumbelv(key0, key1, (uint32_t)row_t * 31999u + (uint32_t)v_t);
  };

  // prologue: chunks 0..3 in sets 0..3; stage chunks 0,1 into bufs 0,1
  ldW(0, 0); ldW(1, 1); ldW(2, 2); ldW(3, 3); ldA(0, 0);
  stW(0, 0); stW(1, 1);
  __syncthreads();
#pragma unroll
  for (int tp = 0; tp < 16; tp += 2) {
    // ---- sub-iter u = tp (even) ----
    if (tp + 4 < 16) ldW((tp + 4) & 3, tp + 4);
    if (tp + 1 < 16) ldA((tp + 1) & 1, tp + 1);
    gum(tp);
    comp(tp & 3, tp & 1);
    if (tp + 2 < 16) stW((tp + 2) & 3, (tp + 2) & 3);
    // ---- sub-iter u = tp+1 (odd) ----
    if (tp + 5 < 16) ldW((tp + 5) & 3, tp + 5);
    if (tp + 2 < 16) ldA((tp + 2) & 1, tp + 2);
    gum(tp + 1);
    comp((tp + 1) & 3, (tp + 1) & 1);
    if (tp + 3 < 16) stW((tp + 3) & 3, (tp + 3) & 3);
    __syncthreads();
  }
  // ---- epilogue: bias + per-row partials (wave-local rows) ----
  float bias_c[4]; int vcol[4];
#pragma unroll
  for (int cf = 0; cf < 4; ++cf) {
    int v = n0 + cf * 16 + l15;
    vcol[cf] = v;
    bias_c[cf] = (v < NV) ? bias[v] : 0.0f;
  }
#pragma unroll
  for (int reg = 0; reg < 4; ++reg) {
    int row = w * 16 + g4 * 4 + reg;   // batch index
    float lv[4], pv[4];
    float mm = -INFINITY;
#pragma unroll
    for (int cf = 0; cf < 4; ++cf) {
      if (vcol[cf] < NV) {
        float l = acc[cf][reg] + bias_c[cf];
        lv[cf] = l; pv[cf] = l + gvv[reg * 4 + cf];
        mm = fmaxf(mm, l);
      } else { lv[cf] = -INFINITY; pv[cf] = -INFINITY; }
    }
    for (int d = 1; d <= 8; d <<= 1) mm = fmaxf(mm, __shfl_xor(mm, d));
    float s1 = 0.0f, s2 = 0.0f;
#pragma unroll
    for (int cf = 0; cf < 4; ++cf)
      if (vcol[cf] < NV) { float t = lv[cf] - mm; float e = expf(t); s1 += e; s2 += e * t; }
    for (int d = 1; d <= 8; d <<= 1) { s1 += __shfl_xor(s1, d); s2 += __shfl_xor(s2, d); }
    float bv = -INFINITY, bl_ = 0.0f; int bi = 0x7fffffff;
#pragma unroll
    for (int cf = 0; cf < 4; ++cf)
      if (pv[cf] > bv || (pv[cf] == bv && vcol[cf] < bi)) { bv = pv[cf]; bi = vcol[cf]; bl_ = lv[cf]; }
    for (int d = 1; d <= 8; d <<= 1) {
      float ov = __shfl_xor(bv, d); int oi = __shfl_xor(bi, d); float ol = __shfl_xor(bl_, d);
      if (ov > bv || (ov == bv && oi < bi)) { bv = ov; bi = oi; bl_ = ol; }
    }
    if (l15 == 0) {
      int o = row * NPB + blockIdx.x;
      vpmax[o] = mm; vps1[o] = s1; vps2[o] = s2;
      vpbv[o] = bv; vpbl[o] = bl_; vpbi[o] = bi;
    }
  }
}

// ================= per-row final reduce + sample + gather (256 thr) =================
__global__ __launch_bounds__(256) void k_final_sample(
    const float* __restrict__ vpmax, const float* __restrict__ vps1,
    const float* __restrict__ vps2, const float* __restrict__ vpbv,
    const float* __restrict__ vpbl, const int* __restrict__ vpbi,
    int t, int* __restrict__ xhist, float* __restrict__ lph,
    float* __restrict__ enth, const float* __restrict__ emb,
    unsigned short* __restrict__ xh, unsigned short* __restrict__ xl) {
  int b = blockIdx.x, tid = threadIdx.x;
  int lane = tid & 63, wv = tid >> 6;
  __shared__ float sM[4], sS1[4], sS2[4], sBV[4], sBL[4];
  __shared__ int sBI[4];
  float M = -INFINITY;
  for (int p = tid; p < NPB; p += 256) M = fmaxf(M, vpmax[b * NPB + p]);
  for (int d = 32; d; d >>= 1) M = fmaxf(M, __shfl_xor(M, d));
  if (lane == 0) sM[wv] = M;
  __syncthreads();
  M = fmaxf(fmaxf(sM[0], sM[1]), fmaxf(sM[2], sM[3]));
  float S1 = 0.0f, S2 = 0.0f, bv = -INFINITY, bl = 0.0f; int bi = 0x7fffffff;
  for (int p = tid; p < NPB; p += 256) {
    int o = b * NPB + p;
    float dm = vpmax[o] - M;
    float sc = expf(dm);
    S1 += vps1[o] * sc;
    S2 += (vps2[o] + dm * vps1[o]) * sc;
    float v = vpbv[o]; int ii = vpbi[o];
    if (v > bv || (v == bv && ii < bi)) { bv = v; bi = ii; bl = vpbl[o]; }
  }
  for (int d = 32; d; d >>= 1) {
    S1 += __shfl_xor(S1, d); S2 += __shfl_xor(S2, d);
    float ov = __shfl_xor(bv, d); int oi = __shfl_xor(bi, d); float ol = __shfl_xor(bl, d);
    if (ov > bv || (ov == bv && oi < bi)) { bv = ov; bi = oi; bl = ol; }
  }
  if (lane == 0) { sS1[wv] = S1; sS2[wv] = S2; sBV[wv] = bv; sBL[wv] = bl; sBI[wv] = bi; }
  __syncthreads();
  S1 = sS1[0] + sS1[1] + sS1[2] + sS1[3];
  S2 = sS2[0] + sS2[1] + sS2[2] + sS2[3];
  bv = -INFINITY; bi = 0x7fffffff; bl = 0.0f;
#pragma unroll
  for (int q = 0; q < 4; ++q) {
    if (sBV[q] > bv || (sBV[q] == bv && sBI[q] < bi)) { bv = sBV[q]; bi = sBI[q]; bl = sBL[q]; }
  }
  float logZ = logf(S1);
  if (tid == 0) {
    xhist[t * 128 + b] = bi;
    lph[t * 128 + b] = bl - M - logZ;
    enth[t * 128 + b] = logZ - S2 / S1;
  }
  const float* er = emb + (size_t)bi * 512;
  for (int k = tid; k < 512; k += 256) {
    unsigned short h_, l_; split2(er[k], h_, l_);
    xh[b * 1024 + k] = h_; xl[b * 1024 + k] = l_;
  }
}

// ================= output epilogue (fp32 out) =================
__global__ void k_finalize(const int* __restrict__ xhist, const float* __restrict__ lph,
                           const float* __restrict__ enth, float* __restrict__ out) {
  int b = blockIdx.x, lane = threadIdx.x;
  int tok = -1, cand = 1 << 20;
  if (lane < NSTEP) {
    tok = xhist[lane * 128 + b];
    if (tok == 1) cand = lane;
  }
  int e = cand;
  for (int d = 32; d; d >>= 1) e = min(e, __shfl_xor(e, d));
  int end_pos = (e >= (1 << 20)) ? 0 : e;
  int seq_len = end_pos + 1;
  if (seq_len == 1) seq_len = NSTEP;
  float ent = 0.0f;
  if (lane < NSTEP) {
    bool msk = lane < seq_len;
    out[b * NSTEP + lane]        = msk ? (float)(tok + 1) : 0.0f;
    out[6400 + b * NSTEP + lane] = msk ? lph[lane * 128 + b] : 0.0f;
    ent = msk ? enth[lane * 128 + b] : 0.0f;
  }
  for (int d = 32; d; d >>= 1) ent += __shfl_xor(ent, d);
  if (lane == 0) out[12800 + b] = ent / (float)seq_len;
}

// ================= host =================
extern "C" void kernel_launch(void* const* d_in, const int* in_sizes, int n_in,
                              void* d_out, int out_size, void* d_ws, size_t ws_size,
                              hipStream_t stream) {
  const float* z    = (const float*)d_in[0];
  const float* emb  = (const float*)d_in[1];
  const float* Wp1  = (const float*)d_in[2];
  const float* bp1  = (const float*)d_in[3];
  const float* Wp2  = (const float*)d_in[4];
  const float* bp2  = (const float*)d_in[5];
  const float* Wih  = (const float*)d_in[6];
  const float* Whh  = (const float*)d_in[7];
  const float* bih  = (const float*)d_in[8];
  const float* bhh  = (const float*)d_in[9];
  const float* Wo1  = (const float*)d_in[10];
  const float* bo1  = (const float*)d_in[11];
  const float* bng  = (const float*)d_in[12];
  const float* bnb  = (const float*)d_in[13];
  const float* bnm  = (const float*)d_in[14];
  const float* bnv  = (const float*)d_in[15];
  const float* Wo2  = (const float*)d_in[16];
  const float* bo2  = (const float*)d_in[17];
  float* out = (float*)d_out;
  (void)in_sizes; (void)n_in; (void)out_size;

  char* base = (char*)d_ws;
  size_t off = 0;
  auto alloc = [&](size_t bytes) -> void* {
    void* p = base + off;
    off = (off + bytes + 255) & ~(size_t)255;
    return p;
  };
  unsigned short* xh[2]; unsigned short* xl[2];
  xh[0] = (unsigned short*)alloc(128 * 1024 * 2);
  xl[0] = (unsigned short*)alloc(128 * 1024 * 2);
  xh[1] = (unsigned short*)alloc(128 * 1024 * 2);
  xl[1] = (unsigned short*)alloc(128 * 1024 * 2);
  float* cbuf = (float*)alloc(128 * 512 * 4);
  unsigned short* rhh = (unsigned short*)alloc(128 * 512 * 2);
  unsigned short* rhl = (unsigned short*)alloc(128 * 512 * 2);
  unsigned short* r2h = (unsigned short*)alloc(128 * 1024 * 2);
  unsigned short* r2l = (unsigned short*)alloc(128 * 1024 * 2);
  float* h1    = (float*)alloc(128 * 1024 * 4);
  float* apart = (float*)alloc((size_t)8 * 128 * 1024 * 4);
  unsigned short* Wgh = (unsigned short*)alloc((size_t)2048 * 1024 * 2);
  unsigned short* Wgl = (unsigned short*)alloc((size_t)2048 * 1024 * 2);
  float* bg = (float*)alloc(2048 * 4);
  unsigned short* Wo1h = (unsigned short*)alloc((size_t)1024 * 512 * 2);
  unsigned short* Wo1l = (unsigned short*)alloc((size_t)1024 * 512 * 2);
  float* Sbn = (float*)alloc(1024 * 4);
  float* Tbn = (float*)alloc(1024 * 4);
  float* vpmax = (float*)alloc((size_t)NPB * 128 * 4);
  float* vps1  = (float*)alloc((size_t)NPB * 128 * 4);
  float* vps2  = (float*)alloc((size_t)NPB * 128 * 4);
  float* vpbv  = (float*)alloc((size_t)NPB * 128 * 4);
  float* vpbl  = (float*)alloc((size_t)NPB * 128 * 4);
  int*   vpbi  = (int*)alloc((size_t)NPB * 128 * 4);
  int*   xhist = (int*)alloc(50 * 128 * 4);
  float* lph   = (float*)alloc(50 * 128 * 4);
  float* enth  = (float*)alloc(50 * 128 * 4);
  size_t wo2_elems = (size_t)NV * 1024;
  bool pre = ws_size >= off + 2 * wo2_elems * 2 + (1 << 20);
  unsigned short* Wo2h = nullptr; unsigned short* Wo2l = nullptr;
  if (pre) {
    Wo2h = (unsigned short*)alloc(wo2_elems * 2);
    Wo2l = (unsigned short*)alloc(wo2_elems * 2);
  }

  // step keys: partitionable split of key(42)
  uint32_t outk[100];
  for (int t = 0; t < 50; ++t) {
    uint32_t y0, y1;
    tf2x32(0u, 42u, 0u, (uint32_t)t, y0, y1);
    outk[2 * t] = y0; outk[2 * t + 1] = y1;
  }

  // prep (every launch; deterministic)
  k_prep_gates<<<1024, 256, 0, stream>>>(Wih, Whh, bih, bhh, Wgh, Wgl, bg);
  k_prep_out1<<<256, 256, 0, stream>>>(Wo1, bo1, bng, bnb, bnm, bnv, Wo1h, Wo1l, Sbn, Tbn);
  if (pre) {
    int total8 = (int)(wo2_elems / 8);
    k_prep_wo2<<<(total8 + 255) / 256, 256, 0, stream>>>(Wo2, Wo2h, Wo2l, total8);
  }

  // prologue: e0 + (h,c) projection
  k_fill_e0<<<256, 256, 0, stream>>>(emb, xh[0], xl[0]);
  gemm_part<<<dim3(16, 4), 256, 0, stream>>>(z, 512, Wp1, Wp1, 512, 512, 1024, 128, apart);
  k_reduce_relu<<<512, 256, 0, stream>>>(apart, 4, bp1, h1, 1024);
  gemm_part<<<dim3(16, 8), 256, 0, stream>>>(h1, 1024, Wp2, Wp2, 1024, 1024, 1024, 128, apart);
  k_reduce_elu_split<<<512, 256, 0, stream>>>(apart, 8, bp2, xh[0], xl[0], cbuf);

  for (int t = 0; t < NSTEP; ++t) {
    int ri = t & 1, wi = ri ^ 1;
    k_gates<<<32, 256, 0, stream>>>(xh[ri], xl[ri], Wgh, Wgl, bg, cbuf,
                                    xh[wi], xl[wi], rhh, rhl);
    k_out1<<<16, 256, 0, stream>>>(rhh, rhl, Wo1h, Wo1l, Sbn, Tbn, r2h, r2l);
    if (pre)
      k_vocab<1><<<NPB, 512, 0, stream>>>(r2h, r2l, Wo2h, Wo2l, Wo2, bo2,
                                          outk[2 * t], outk[2 * t + 1],
                                          vpmax, vps1, vps2, vpbv, vpbl, vpbi);
    else
      k_vocab<0><<<NPB, 512, 0, stream>>>(r2h, r2l, nullptr, nullptr, Wo2, bo2,
                                          outk[2 * t], outk[2 * t + 1],
                                          vpmax, vps1, vps2, vpbv, vpbl, vpbi);
    k_final_sample<<<128, 256, 0, stream>>>(vpmax, vps1, vps2, vpbv, vpbl, vpbi,
                                            t, xhist, lph, enth, emb, xh[wi], xl[wi]);
  }
  k_finalize<<<128, 64, 0, stream>>>(xhist, lph, enth, out);
}